// Round 6
// baseline (182.328 us; speedup 1.0000x reference)
//
#include <hip/hip_runtime.h>

typedef __bf16 bf16x8 __attribute__((ext_vector_type(8)));
typedef float floatx16 __attribute__((ext_vector_type(16)));
typedef float floatx4 __attribute__((ext_vector_type(4)));

#define T_ 4096
#define STK 72      // LDS row stride (shorts) for attn1 V/P tiles
#define XSTR 40     // proj x-tile row stride (shorts): 80B rows, 16B-aligned, 2-way banks
#define NSPB 272    // split-blocks per batch: sum_{qt=0..31} ceil((qt+1)/2)

// ws layout (bytes)
#define WT_OFF 0u
#define Q_OFF  393216u
#define K_OFF  2490368u
#define V_OFF  4587520u
#define OP_OFF 6684672u
#define ML_OFF 42336256u   // OP_OFF + 4*NSPB*8192*4

__device__ __forceinline__ unsigned short bf16bits(float f) {
  __bf16 h = (__bf16)f;
  return __builtin_bit_cast(unsigned short, h);
}

// async global->LDS 16B: LDS dest is wave-uniform base + lane*16 (m97/m104)
__device__ __forceinline__ void async16(const void* g, void* l) {
  __builtin_amdgcn_global_load_lds((const __attribute__((address_space(1))) void*)g,
                                   (__attribute__((address_space(3))) void*)l, 16, 0, 0);
}

// ---------------- kernel 0: W -> W^T bf16, fold softmax scale into Wq ----------------
__global__ void wprep(const float* __restrict__ Wq, const float* __restrict__ Wk,
                      const float* __restrict__ Wv, __bf16* __restrict__ Wtg) {
  int idx = blockIdx.x * 256 + threadIdx.x;      // 0..196607
  int mat = idx >> 16;
  int r = idx & 65535;
  int h = r & 63;
  int k = r >> 6;
  const float* W = (mat == 0) ? Wq : ((mat == 1) ? Wk : Wv);
  float v = W[k * 64 + h];
  if (mat == 0) v *= 0.03125f * 1.4426950408889634f;  // C^-0.5 * log2(e)
  Wtg[(size_t)(mat * 64 + h) * 1024 + k] = (__bf16)v;
}

// ---------------- kernel 1: QKV projection (x fp32 -> Q~,K,V bf16) ----------------
// 16 rows x 192 cols per block, grid 1024 -> 4 blocks/CU (LDS 26.5KB). K-chunk 32,
// double-buffered, 1 barrier/chunk. W via global_load_lds(16B) into 2-bit-XOR-swizzled
// slots (2-way banks = free). 4 waves = 4 col-groups of 48.
__global__ __launch_bounds__(256, 4) void proj(const float* __restrict__ x,
                                               const __bf16* __restrict__ Wtg,
                                               __bf16* __restrict__ Qp,
                                               __bf16* __restrict__ Kp,
                                               __bf16* __restrict__ Vp) {
  // xt: 2 x [16][XSTR] shorts ; wt: 2 x [192 rows][32 k] shorts (swizzled 16B slots)
  __shared__ __align__(16) unsigned short sm[2 * 16 * XSTR + 2 * 6144];
  unsigned short* xt = sm;
  unsigned short* wt = sm + 2 * 16 * XSTR;

  const int tid = threadIdx.x;
  const int wave = tid >> 6, lane = tid & 63;
  const int l15 = lane & 15, quad = lane >> 4;
  const size_t row0 = (size_t)blockIdx.x * 16;

  // x staging: threads 0..127 stage the 16x32 fp32 chunk (float4 each)
  const int xrow = tid >> 3, xc4 = (tid & 7) * 4;
  const float* xsrc = (tid < 128) ? (x + (row0 + xrow) * 1024 + xc4) : x;
  // W staging: 3 async16 issues/chunk; row R = i*64 + (tid>>2), local slot = tid&3
  const int wR0 = tid >> 2, wsl = tid & 3;

  floatx4 acc[3];
#pragma unroll
  for (int t = 0; t < 3; t++)
#pragma unroll
    for (int i = 0; i < 4; i++) acc[t][i] = 0.0f;

  // ---- stage chunk 0 into buf 0 ----
  {
    unsigned short* wb = wt;
#pragma unroll
    for (int i = 0; i < 3; i++) {
      int R = wR0 + i * 64;
      int sg = wsl ^ (R & 3);
      async16((const char*)Wtg + (size_t)R * 2048 + sg * 16,
              (char*)(wb + (i * 256 + wave * 64) * 8));
    }
    if (tid < 128) {
      float4 f = *(const float4*)(xsrc);
      unsigned short hb[4];
      hb[0] = bf16bits(f.x); hb[1] = bf16bits(f.y); hb[2] = bf16bits(f.z); hb[3] = bf16bits(f.w);
      *(uint2*)&xt[xrow * XSTR + xc4] = *(uint2*)(hb);
    }
  }
  __syncthreads();

  for (int kc = 0; kc < 32; ++kc) {
    const int cur = kc & 1;
    if (kc < 31) {  // stage chunk kc+1 into other buffer (drained at end barrier)
      unsigned short* wb = wt + (cur ^ 1) * 6144;
#pragma unroll
      for (int i = 0; i < 3; i++) {
        int R = wR0 + i * 64;
        int sg = wsl ^ (R & 3);
        async16((const char*)Wtg + (size_t)R * 2048 + (kc + 1) * 64 + sg * 16,
                (char*)(wb + (i * 256 + wave * 64) * 8));
      }
      if (tid < 128) {
        float4 f = *(const float4*)(xsrc + (kc + 1) * 32);
        unsigned short hb[4];
        hb[0] = bf16bits(f.x); hb[1] = bf16bits(f.y); hb[2] = bf16bits(f.z); hb[3] = bf16bits(f.w);
        *(uint2*)&xt[(cur ^ 1) * 16 * XSTR + xrow * XSTR + xc4] = *(uint2*)(hb);
      }
    }
    // compute on cur: 3 MFMA/wave (wave = col-group of 48)
    const unsigned short* xb = xt + cur * 16 * XSTR;
    const unsigned short* wb = wt + cur * 6144;
    bf16x8 a = *(const bf16x8*)&xb[l15 * XSTR + quad * 8];
#pragma unroll
    for (int ht = 0; ht < 3; ++ht) {
      int Rg = wave * 48 + ht * 16 + l15;
      bf16x8 b = *(const bf16x8*)&wb[Rg * 32 + ((quad ^ (Rg & 3))) * 8];
      acc[ht] = __builtin_amdgcn_mfma_f32_16x16x32_bf16(a, b, acc[ht], 0, 0, 0);
    }
    __syncthreads();
  }
  // epilogue: C layout col=lane&15, row=quad*4+reg
#pragma unroll
  for (int ht = 0; ht < 3; ++ht) {
    int g0 = wave * 48 + ht * 16;        // global output col base (0..191)
    int mat = g0 >> 6, h0 = g0 & 63;
    __bf16* outp = (mat == 0) ? Qp : ((mat == 1) ? Kp : Vp);
#pragma unroll
    for (int r = 0; r < 4; r++) {
      size_t row = row0 + quad * 4 + r;
      outp[row * 64 + h0 + l15] = (__bf16)acc[ht][r];
    }
  }
}

// ---------------- kernel 2: flash attention pass 1 (split-K partials) ----------------
// K-frags direct from L2 (no K staging); V prefetched to regs during compute, committed
// to LDS between barriers (critical section = 8 ds_write_b32 only). 4 blocks/CU.
__global__ __launch_bounds__(256, 4) void attn1(const __bf16* __restrict__ Qp,
                                                const __bf16* __restrict__ Kp,
                                                const __bf16* __restrict__ Vp,
                                                float* __restrict__ Opart,
                                                float* __restrict__ mlpart) {
  __shared__ __align__(16) unsigned char smraw[36864];
  unsigned short* Vtl = (unsigned short*)smraw;  // [64 h][STK] (V transposed)
  unsigned short* Pl = Vtl + 64 * STK;           // [4 waves][32][STK]
  float* Oe = (float*)smraw;                     // epilogue reuse: [128][68] = 34816B

  const int tid = threadIdx.x;
  const int wave = tid >> 6, lane = tid & 63;
  const int l31 = lane & 31, half = lane >> 5;

  const int bid = blockIdx.x;
  const int b = bid / NSPB;
  const int f = bid - b * NSPB;
  int qt = 0, cum = 0;
  for (;;) { int s = (qt + 2) >> 1; if (f < cum + s) break; cum += s; qt++; }
  const int si = f - cum;
  const int S = (qt + 2) >> 1;
  const int n_iters = 2 * (qt + 1);
  const int bbase = n_iters / S, rem = n_iters % S;
  const int it0 = si * bbase + (si < rem ? si : rem);
  const int it1 = it0 + bbase + (si < rem ? 1 : 0);

  const int qb = qt * 128;
  const size_t brow = (size_t)b * 4096;

  bf16x8 qf[4];
  {
    const __bf16* qptr = Qp + (brow + qb + wave * 32 + l31) * 64 + half * 8;
#pragma unroll
    for (int ks = 0; ks < 4; ks++) qf[ks] = *(const bf16x8*)(qptr + ks * 16);
  }

  floatx16 o0, o1;
#pragma unroll
  for (int r = 0; r < 16; r++) { o0[r] = 0.0f; o1[r] = 0.0f; }
  float m_run = -1e30f, l_run = 0.0f;
  unsigned short* Pw = Pl + wave * 32 * STK;
  const int qrow = qb + wave * 32 + l31;

  const int vkp = tid & 31, vh0 = ((tid >> 5) & 7) * 8;
  const __bf16* vbase = Vp + brow * 64;

  // pre-stage V(it0)
  {
    const __bf16* vp = vbase + (size_t)(it0 * 64 + 2 * vkp) * 64 + vh0;
    uint4 va4 = *(const uint4*)vp;
    uint4 vb4 = *(const uint4*)(vp + 64);
    const unsigned short* pa = (const unsigned short*)&va4;
    const unsigned short* pb = (const unsigned short*)&vb4;
#pragma unroll
    for (int j = 0; j < 8; j++) {
      unsigned int w = (unsigned int)pa[j] | ((unsigned int)pb[j] << 16);
      *(unsigned int*)&Vtl[(vh0 + j) * STK + 2 * vkp] = w;
    }
  }
  __syncthreads();

  for (int it = it0; it < it1; ++it) {
    const int k0 = it * 64;
    const bool hasnext = (it + 1 < it1);
    // prefetch next V tile into registers (latency hidden behind QK/softmax/PV)
    uint4 nva, nvb;
    if (hasnext) {
      const __bf16* vp = vbase + (size_t)((it + 1) * 64 + 2 * vkp) * 64 + vh0;
      nva = *(const uint4*)vp;
      nvb = *(const uint4*)(vp + 64);
    }
    // S^T = K @ Q^T, K-frags straight from global (L2-resident)
    const __bf16* kp0 = Kp + (brow + k0) * 64;
    floatx16 s0, s1;
#pragma unroll
    for (int r = 0; r < 16; r++) { s0[r] = 0.0f; s1[r] = 0.0f; }
#pragma unroll
    for (int ks = 0; ks < 4; ks++) {
      bf16x8 ka = *(const bf16x8*)(kp0 + l31 * 64 + ks * 16 + half * 8);
      bf16x8 kb = *(const bf16x8*)(kp0 + (32 + l31) * 64 + ks * 16 + half * 8);
      s0 = __builtin_amdgcn_mfma_f32_32x32x16_bf16(ka, qf[ks], s0, 0, 0, 0);
      s1 = __builtin_amdgcn_mfma_f32_32x32x16_bf16(kb, qf[ks], s1, 0, 0, 0);
    }
    if (k0 + 64 > qb) {  // diagonal: causal mask (key > q -> -inf)
#pragma unroll
      for (int r = 0; r < 16; r++) {
        int rs = (r & 3) + 8 * (r >> 2) + 4 * half;
        if (k0 + rs > qrow) s0[r] = -1e30f;
        if (k0 + 32 + rs > qrow) s1[r] = -1e30f;
      }
    }
    // online softmax: one q-row per lane (col=lane&31)
    float pm = -1e30f;
#pragma unroll
    for (int r = 0; r < 16; r++) { pm = fmaxf(pm, s0[r]); pm = fmaxf(pm, s1[r]); }
    pm = fmaxf(pm, __shfl_xor(pm, 32));
    float m_new = fmaxf(m_run, pm);
    float alpha = __builtin_amdgcn_exp2f(m_run - m_new);
    float psum = 0.0f;
#pragma unroll
    for (int r = 0; r < 16; r++) {
      s0[r] = __builtin_amdgcn_exp2f(s0[r] - m_new);
      s1[r] = __builtin_amdgcn_exp2f(s1[r] - m_new);
      psum += s0[r] + s1[r];
    }
    psum += __shfl_xor(psum, 32);
    l_run = l_run * alpha + psum;
    m_run = m_new;
#pragma unroll
    for (int r = 0; r < 16; r++) { o0[r] *= alpha; o1[r] *= alpha; }
    // P -> LDS [q][key] bf16 (wave-private)
#pragma unroll
    for (int g = 0; g < 4; ++g) {
      int kb0 = 8 * g + 4 * half;
      unsigned int w0 = (unsigned int)bf16bits(s0[4 * g]) | ((unsigned int)bf16bits(s0[4 * g + 1]) << 16);
      unsigned int w1 = (unsigned int)bf16bits(s0[4 * g + 2]) | ((unsigned int)bf16bits(s0[4 * g + 3]) << 16);
      *(uint2*)&Pw[l31 * STK + kb0] = make_uint2(w0, w1);
      unsigned int w2 = (unsigned int)bf16bits(s1[4 * g]) | ((unsigned int)bf16bits(s1[4 * g + 1]) << 16);
      unsigned int w3 = (unsigned int)bf16bits(s1[4 * g + 2]) | ((unsigned int)bf16bits(s1[4 * g + 3]) << 16);
      *(uint2*)&Pw[l31 * STK + 32 + kb0] = make_uint2(w2, w3);
    }
    // O^T += V^T @ P^T
#pragma unroll
    for (int kst = 0; kst < 4; ++kst) {
      bf16x8 pf = *(const bf16x8*)&Pw[l31 * STK + kst * 16 + half * 8];
      bf16x8 va = *(const bf16x8*)&Vtl[l31 * STK + kst * 16 + half * 8];
      bf16x8 vb = *(const bf16x8*)&Vtl[(32 + l31) * STK + kst * 16 + half * 8];
      o0 = __builtin_amdgcn_mfma_f32_32x32x16_bf16(va, pf, o0, 0, 0, 0);
      o1 = __builtin_amdgcn_mfma_f32_32x32x16_bf16(vb, pf, o1, 0, 0, 0);
    }
    __syncthreads();   // all waves done reading Vtl
    if (hasnext) {     // commit prefetched V (LDS writes only — cheap critical section)
      const unsigned short* pa = (const unsigned short*)&nva;
      const unsigned short* pb = (const unsigned short*)&nvb;
#pragma unroll
      for (int j = 0; j < 8; j++) {
        unsigned int w = (unsigned int)pa[j] | ((unsigned int)pb[j] << 16);
        *(unsigned int*)&Vtl[(vh0 + j) * STK + 2 * vkp] = w;
      }
    }
    __syncthreads();
  }
  // epilogue: transpose O^T -> Oe[q][h] in LDS, then coalesced partial store
#pragma unroll
  for (int r = 0; r < 16; r++) {
    int rs = (r & 3) + 8 * (r >> 2) + 4 * half;
    Oe[(wave * 32 + l31) * 68 + rs] = o0[r];
    Oe[(wave * 32 + l31) * 68 + 32 + rs] = o1[r];
  }
  if (lane < 32) {
    mlpart[(size_t)bid * 256 + wave * 32 + l31] = m_run;
    mlpart[(size_t)bid * 256 + 128 + wave * 32 + l31] = l_run;
  }
  __syncthreads();
  {
    float* dst = Opart + (size_t)bid * 8192;
    int r = tid >> 1, hh = (tid & 1) * 32;
#pragma unroll
    for (int i = 0; i < 8; i++)
      *(float4*)&dst[r * 64 + hh + 4 * i] = *(float4*)&Oe[r * 68 + hh + 4 * i];
  }
}

// ---------------- kernel 3: merge split partials, normalize ----------------
__global__ __launch_bounds__(256, 4) void attn2(const float* __restrict__ Opart,
                                                const float* __restrict__ mlpart,
                                                float* __restrict__ out) {
  const int bid = blockIdx.x;  // 0..511
  const int b = bid >> 7, rg = bid & 127;
  const int qt = rg >> 2;
  int cum = 0;
  for (int i = 0; i < qt; i++) cum += (i + 2) >> 1;
  const int S = (qt + 2) >> 1;
  const int t = threadIdx.x;
  const int r = t >> 3;
  const int prow = (rg & 3) * 32 + r;
  const int h0 = (t & 7) * 8;

  float M = -1e30f;
  for (int s = 0; s < S; s++)
    M = fmaxf(M, mlpart[(size_t)(b * NSPB + cum + s) * 256 + prow]);
  float a[8];
#pragma unroll
  for (int i = 0; i < 8; i++) a[i] = 0.0f;
  float L = 0.0f;
  for (int s = 0; s < S; s++) {
    size_t pb = (size_t)(b * NSPB + cum + s);
    float w = __builtin_amdgcn_exp2f(mlpart[pb * 256 + prow] - M);
    L += w * mlpart[pb * 256 + 128 + prow];
    const float* op = Opart + pb * 8192 + prow * 64 + h0;
    float4 v0 = *(const float4*)op;
    float4 v1 = *(const float4*)(op + 4);
    a[0] += w * v0.x; a[1] += w * v0.y; a[2] += w * v0.z; a[3] += w * v0.w;
    a[4] += w * v1.x; a[5] += w * v1.y; a[6] += w * v1.z; a[7] += w * v1.w;
  }
  float inv = 1.0f / L;
  float* po = out + ((size_t)b * 4096 + rg * 32 + r) * 64 + h0;
  float4 r0, r1;
  r0.x = a[0] * inv; r0.y = a[1] * inv; r0.z = a[2] * inv; r0.w = a[3] * inv;
  r1.x = a[4] * inv; r1.y = a[5] * inv; r1.z = a[6] * inv; r1.w = a[7] * inv;
  *(float4*)po = r0;
  *(float4*)(po + 4) = r1;
}

extern "C" void kernel_launch(void* const* d_in, const int* in_sizes, int n_in,
                              void* d_out, int out_size, void* d_ws, size_t ws_size,
                              hipStream_t stream) {
  (void)in_sizes; (void)n_in; (void)out_size; (void)ws_size;
  const float* x = (const float*)d_in[0];
  const float* Wq = (const float*)d_in[1];
  const float* Wk = (const float*)d_in[2];
  const float* Wv = (const float*)d_in[3];
  char* ws = (char*)d_ws;
  __bf16* Wtg = (__bf16*)(ws + WT_OFF);
  __bf16* Qp = (__bf16*)(ws + Q_OFF);
  __bf16* Kp = (__bf16*)(ws + K_OFF);
  __bf16* Vp = (__bf16*)(ws + V_OFF);
  float* Opart = (float*)(ws + OP_OFF);
  float* mlp = (float*)(ws + ML_OFF);
  float* out = (float*)d_out;

  hipLaunchKernelGGL(wprep, dim3(768), dim3(256), 0, stream, Wq, Wk, Wv, Wtg);
  hipLaunchKernelGGL(proj, dim3(1024), dim3(256), 0, stream, x, Wtg, Qp, Kp, Vp);
  hipLaunchKernelGGL(attn1, dim3(4 * NSPB), dim3(256), 0, stream, Qp, Kp, Vp, Opart, mlp);
  hipLaunchKernelGGL(attn2, dim3(512), dim3(256), 0, stream, Opart, mlp, out);
}